// Round 1
// baseline (251.065 us; speedup 1.0000x reference)
//
#include <hip/hip_runtime.h>
#include <hip/hip_bf16.h>
#include <math.h>

#define HIDDEN 1024
#define HEADS 16
#define HEAD_DIM 64
#define EPS 1e-5f

typedef __attribute__((ext_vector_type(8))) short bf16x8;
typedef __attribute__((ext_vector_type(4))) float f32x4;

#if defined(__has_builtin)
#if __has_builtin(__builtin_amdgcn_exp2f)
#define EXP2(x) __builtin_amdgcn_exp2f(x)
#endif
#endif
#ifndef EXP2
#define EXP2(x) exp2f(x)
#endif

// 0.125 (1/sqrt(64)) * log2(e): folded into Wq/bq so softmax is exp2(s)
#define QSCALE 0.18033688011112042f

__device__ __forceinline__ short f2bf(float f) {
    union { float f; unsigned u; } v; v.f = f;
    unsigned r = v.u + 0x7fffu + ((v.u >> 16) & 1u);   // RNE
    return (short)(r >> 16);
}

// async global->LDS DMA, 16 B per lane; dest = ldsbase + lane*16 (wave-uniform base)
__device__ __forceinline__ void gl_lds16(const void* g, void* l) {
    __builtin_amdgcn_global_load_lds(
        (const __attribute__((address_space(1))) void*)g,
        (__attribute__((address_space(3))) void*)l, 16, 0, 0);
}

// ---------------------------------------------------------------------------
// fp32 -> bf16 cast, 4 elems/thread
// ---------------------------------------------------------------------------
__global__ __launch_bounds__(256) void cast_bf16_kernel(
    const float* __restrict__ in, short* __restrict__ out, int n)
{
    int i = (blockIdx.x * 256 + threadIdx.x) * 4;
    if (i >= n) return;
    float4 v = *(const float4*)(in + i);
    short o[4] = { f2bf(v.x), f2bf(v.y), f2bf(v.z), f2bf(v.w) };
    *(uint2*)(out + i) = *(uint2*)o;
}

// ---------------------------------------------------------------------------
// All 4 weights: W[K,N] fp32 -> Wt[N,K] bf16 (32x32 tiles), z picks weight
// ---------------------------------------------------------------------------
__global__ __launch_bounds__(256) void wtrans_kernel(
    const float* __restrict__ Wq, const float* __restrict__ Wk,
    const float* __restrict__ Wv, const float* __restrict__ Wo,
    short* __restrict__ Wt3, short* __restrict__ Wot)
{
    const int wsel = blockIdx.z;
    const float* W = (wsel == 0) ? Wq : (wsel == 1) ? Wk : (wsel == 2) ? Wv : Wo;
    short* dst = (wsel < 3) ? (Wt3 + (size_t)wsel * 1024 * 1024) : Wot;
    const float scale = (wsel == 0) ? QSCALE : 1.0f;

    __shared__ short tile[32][33];
    int n0 = blockIdx.x * 32;
    int k0 = blockIdx.y * 32;
    int tx = threadIdx.x & 31;
    int ty = threadIdx.x >> 5;  // 0..7
    #pragma unroll
    for (int i = 0; i < 32; i += 8)
        tile[ty + i][tx] = f2bf(W[(size_t)(k0 + ty + i) * 1024 + n0 + tx] * scale);
    __syncthreads();
    #pragma unroll
    for (int i = 0; i < 32; i += 8)
        dst[(size_t)(n0 + ty + i) * 1024 + k0 + tx] = tile[tx][ty + i];
}

// ---------------------------------------------------------------------------
// b3 = concat(bq*qscale, bk, bv)
// ---------------------------------------------------------------------------
__global__ __launch_bounds__(256) void concat_bias_kernel(
    const float* __restrict__ bq, const float* __restrict__ bk,
    const float* __restrict__ bv, float* __restrict__ b3)
{
    int i = blockIdx.x * 256 + threadIdx.x;
    if (i >= 3072) return;
    float v = (i < 1024) ? bq[i] * QSCALE
            : (i < 2048) ? bk[i - 1024] : bv[i - 2048];
    b3[i] = v;
}

// ---------------------------------------------------------------------------
// C[M,N] = A[M,K] @ Bt[N,K]^T + bias[col] (+ resid fp32 if given).
// 128x128 tile, BK=32, 4 waves. Staging via global_load_lds (16B DMA),
// XOR-swizzled source columns so LDS is unpadded yet fragment reads are
// bank-balanced. Columns >= split_col go to C1 (rebased), else C0.
// ---------------------------------------------------------------------------
__global__ __launch_bounds__(256) void gemm_bt_mfma(
    const short* __restrict__ A, const short* __restrict__ Bt,
    const float* __restrict__ bias,
    void* __restrict__ C0, int ldc0,
    void* __restrict__ C1, int split_col, int ldc1,
    const float* __restrict__ resid,
    int M, int N, int K, int out_bf16)
{
    __shared__ short As[128 * 32];
    __shared__ short Bs[128 * 32];
    const int tid = threadIdx.x;
    const int wave = tid >> 6, lane = tid & 63;
    const int ln16 = lane & 15, quad = lane >> 4;
    const int wm = (wave >> 1) * 64, wn = (wave & 1) * 64;
    const int brow = blockIdx.y * 128, bcol = blockIdx.x * 128;

    const int sr  = lane >> 2;   // 0..15 row within 16-row chunk
    const int scb = lane & 3;    // lds col-block (8 shorts)

    f32x4 acc[4][4];
    #pragma unroll
    for (int mt = 0; mt < 4; ++mt)
        #pragma unroll
        for (int nt = 0; nt < 4; ++nt) acc[mt][nt] = (f32x4){0.f, 0.f, 0.f, 0.f};

    for (int k0 = 0; k0 < K; k0 += 32) {
        __syncthreads();
        #pragma unroll
        for (int i = 0; i < 2; ++i) {
            int rb = i * 64 + wave * 16;          // chunk base row (wave-uniform)
            int r  = rb + sr;
            int csrc = (scb ^ ((r >> 1) & 3)) * 8;
            gl_lds16(A  + (size_t)(brow + r) * K + k0 + csrc, &As[rb * 32]);
            gl_lds16(Bt + (size_t)(bcol + r) * K + k0 + csrc, &Bs[rb * 32]);
        }
        __syncthreads();

        bf16x8 af[4], bf[4];
        #pragma unroll
        for (int mt = 0; mt < 4; ++mt) {
            int r = wm + mt * 16 + ln16;
            af[mt] = *(const bf16x8*)&As[r * 32 + ((quad ^ ((r >> 1) & 3)) * 8)];
        }
        #pragma unroll
        for (int nt = 0; nt < 4; ++nt) {
            int r = wn + nt * 16 + ln16;
            bf[nt] = *(const bf16x8*)&Bs[r * 32 + ((quad ^ ((r >> 1) & 3)) * 8)];
        }
        #pragma unroll
        for (int mt = 0; mt < 4; ++mt)
            #pragma unroll
            for (int nt = 0; nt < 4; ++nt)
                acc[mt][nt] = __builtin_amdgcn_mfma_f32_16x16x32_bf16(
                    af[mt], bf[nt], acc[mt][nt], 0, 0, 0);
    }

    void* Cp = C0; int ld = ldc0; int coff = 0;
    if (bcol >= split_col) { Cp = C1; ld = ldc1; coff = split_col; }

    #pragma unroll
    for (int mt = 0; mt < 4; ++mt) {
        #pragma unroll
        for (int r = 0; r < 4; ++r) {
            int row = brow + wm + mt * 16 + quad * 4 + r;
            #pragma unroll
            for (int nt = 0; nt < 4; ++nt) {
                int col = bcol + wn + nt * 16 + ln16;
                float v = acc[mt][nt][r] + bias[col];
                if (resid) v += resid[(size_t)row * N + col];
                if (out_bf16) ((short*)Cp)[(size_t)row * ld + (col - coff)] = f2bf(v);
                else          ((float*)Cp)[(size_t)row * ld + (col - coff)] = v;
            }
        }
    }
}

// ---------------------------------------------------------------------------
// Vb[4096][1024] bf16 -> VT[1024][4096] bf16, 64x64 tiles
// ---------------------------------------------------------------------------
__global__ __launch_bounds__(256) void vtranspose_kernel(
    const short* __restrict__ Vb, short* __restrict__ VT)
{
    __shared__ short t[64][72];
    const int c0 = blockIdx.x * 64;    // feature block
    const int r0 = blockIdx.y * 64;    // token block
    const int tid = threadIdx.x;
    #pragma unroll
    for (int i = 0; i < 2; ++i) {
        int idx = tid + i * 256;
        int r = idx >> 3, cc = (idx & 7) * 8;
        *(uint4*)&t[r][cc] = *(const uint4*)(Vb + (size_t)(r0 + r) * 1024 + c0 + cc);
    }
    __syncthreads();
    #pragma unroll
    for (int i = 0; i < 2; ++i) {
        int idx = tid + i * 256;
        int c = idx >> 3, rr = (idx & 7) * 8;
        short tmp[8];
        #pragma unroll
        for (int j = 0; j < 8; ++j) tmp[j] = t[rr + j][c];
        *(uint4*)(VT + (size_t)(c0 + c) * 4096 + r0 + rr) = *(uint4*)tmp;
    }
}

// ---------------------------------------------------------------------------
// MFMA flash attention, fixed-max softmax (p = exp2(s); scale pre-folded).
// QKb[4096][2048]: Q cols 0..1023, K cols 1024..2047.  VT[1024][4096] = V^T.
// Block = (h, qt, b): 64 q-rows; 4 waves, wave owns 16 q-rows.
// K/V tiles DOUBLE-BUFFERED via global_load_lds with counted vmcnt + raw
// s_barriers (no vmcnt(0) drain): tile kt+1's DMA flies under tile kt's
// compute.  S^T trick (A=K, B=Q) -> b64 P writes / b128 P reads; Ps is
// XOR-swizzled at 16B granularity (pitch 64, no pad) so LDS = 40960 B
// exactly -> 4 blocks/CU.  Grid (16,32,2)=1024 blocks = 4/CU; h-major so
// each XCD's L2 holds 2 heads' K/V stream.
// ---------------------------------------------------------------------------
__global__ __launch_bounds__(256, 4) void attn_mfma_kernel(
    const short* __restrict__ QKb, const short* __restrict__ VT,
    short* __restrict__ Ctx)
{
    const int S = 2048;
    const int NT = S / 64;
    const int h = blockIdx.x, qt = blockIdx.y, b = blockIdx.z;
    const int tid = threadIdx.x;
    const int wave = tid >> 6, lane = tid & 63;
    const int ln16 = lane & 15, quad = lane >> 4;

    __shared__ short Ks[2][64 * 64];   // [buf][k-token][d], swizzled   (16 KB)
    __shared__ short Vs[2][64 * 64];   // [buf][d][k-token], swizzled   (16 KB)
    __shared__ short Ps[64 * 64];      // [q][k-token], 16B-XOR-swizzled (8 KB)

    const int q0 = qt * 64 + wave * 16;

    // Q fragments (B-operand), straight from global, live in registers
    bf16x8 qfrag[2];
    #pragma unroll
    for (int kb = 0; kb < 2; ++kb)
        qfrag[kb] = *(const bf16x8*)(QKb +
            (size_t)(b * S + q0 + ln16) * 2048 + h * 64 + kb * 32 + quad * 8);

    bf16x8 ones;
    #pragma unroll
    for (int j = 0; j < 8; ++j) ones[j] = (short)0x3F80;  // bf16 1.0

    f32x4 of[4], lacc = (f32x4){0.f, 0.f, 0.f, 0.f};
    #pragma unroll
    for (int nt = 0; nt < 4; ++nt) of[nt] = (f32x4){0.f, 0.f, 0.f, 0.f};

    const int sr  = lane >> 3;   // 0..7 row within 8-row chunk
    const int scb = lane & 7;    // lds col-block

    // stage tile kt into buffer p: 4 DMA per wave (2 K-chunks + 2 V-chunks)
    auto stage = [&](int p, int kt) {
        #pragma unroll
        for (int i = 0; i < 2; ++i) {
            int ci = wave * 2 + i;            // chunk 0..7 (8 rows each)
            int r  = ci * 8 + sr;             // 0..63
            int csrc = ((scb ^ (r & 7))) * 8;
            gl_lds16(QKb + (size_t)(b * S + kt * 64 + r) * 2048 + 1024 + h * 64 + csrc,
                     &Ks[p][ci * 512]);
            gl_lds16(VT + (size_t)(h * 64 + r) * 4096 + b * S + kt * 64 + csrc,
                     &Vs[p][ci * 512]);
        }
    };

    const int prow = wave * 16 + ln16;        // Ps row this lane owns
    const int pkey = prow & 7;                // 16B-block swizzle key

    stage(0, 0);

    for (int kt = 0; kt < NT; ++kt) {
        const int p = kt & 1;

        if (kt + 1 < NT) {
            stage(p ^ 1, kt + 1);             // next tile's DMA: stays in flight
            asm volatile("s_waitcnt vmcnt(4)" ::: "memory");   // own prev 4 done
        } else {
            asm volatile("s_waitcnt vmcnt(0)" ::: "memory");
        }
        __builtin_amdgcn_s_barrier();          // buf[p] fully written, all waves
        __builtin_amdgcn_sched_barrier(0);

        const short* ks = Ks[p];
        const short* vs = Vs[p];

        // S^T = K Q^T ; exp2 ; pack 4 consecutive-k bf16 -> b64 swizzled write
        #pragma unroll
        for (int nt = 0; nt < 4; ++nt) {
            bf16x8 kf[2];
            #pragma unroll
            for (int kb = 0; kb < 2; ++kb) {
                int r = nt * 16 + ln16;
                int cb = (kb * 4 + quad) ^ (r & 7);
                kf[kb] = *(const bf16x8*)&ks[r * 64 + cb * 8];
            }
            f32x4 a = (f32x4){0.f, 0.f, 0.f, 0.f};
            a = __builtin_amdgcn_mfma_f32_16x16x32_bf16(kf[0], qfrag[0], a, 0, 0, 0);
            a = __builtin_amdgcn_mfma_f32_16x16x32_bf16(kf[1], qfrag[1], a, 0, 0, 0);
            float p0 = EXP2(a[0]), p1 = EXP2(a[1]);
            float p2 = EXP2(a[2]), p3 = EXP2(a[3]);
            union { __hip_bfloat162 h2; unsigned u; } c01, c23;
            c01.h2 = __float22bfloat162_rn(make_float2(p0, p1));
            c23.h2 = __float22bfloat162_rn(make_float2(p2, p3));
            uint2 w; w.x = c01.u; w.y = c23.u;
            // unswizzled byte col = nt*32 + quad*8 -> 16B block c16, 8B half
            int c16 = nt * 2 + (quad >> 1);
            int cby = ((c16 ^ pkey) << 4) | ((quad & 1) << 3);
            *(uint2*)((char*)Ps + prow * 128 + cby) = w;
        }

        // P fragments (per-wave private region: no barrier needed)
        bf16x8 pf[2];
        #pragma unroll
        for (int kb = 0; kb < 2; ++kb) {
            int c16 = (kb * 4 + quad) ^ pkey;
            pf[kb] = *(const bf16x8*)((const char*)Ps + prow * 128 + (c16 << 4));
        }

        lacc = __builtin_amdgcn_mfma_f32_16x16x32_bf16(pf[0], ones, lacc, 0, 0, 0);
        lacc = __builtin_amdgcn_mfma_f32_16x16x32_bf16(pf[1], ones, lacc, 0, 0, 0);

        #pragma unroll
        for (int nt = 0; nt < 4; ++nt) {
            bf16x8 vf[2];
            #pragma unroll
            for (int kb = 0; kb < 2; ++kb) {
                int r = nt * 16 + ln16;
                int cb = (kb * 4 + quad) ^ (r & 7);
                vf[kb] = *(const bf16x8*)&vs[r * 64 + cb * 8];
            }
            of[nt] = __builtin_amdgcn_mfma_f32_16x16x32_bf16(pf[0], vf[0], of[nt], 0, 0, 0);
            of[nt] = __builtin_amdgcn_mfma_f32_16x16x32_bf16(pf[1], vf[1], of[nt], 0, 0, 0);
        }

        __builtin_amdgcn_sched_barrier(0);
        __builtin_amdgcn_s_barrier();          // all waves done reading buf[p]
    }

    #pragma unroll
    for (int r = 0; r < 4; ++r) {
        float inv = 1.f / lacc[r];
        int row = b * S + qt * 64 + wave * 16 + quad * 4 + r;
        #pragma unroll
        for (int nt = 0; nt < 4; ++nt)
            Ctx[(size_t)row * 1024 + h * 64 + nt * 16 + ln16] =
                f2bf(of[nt][r] * inv);
    }
}

// ---------------------------------------------------------------------------
// out = LayerNorm(x) * gamma + beta (residual already folded into x).
// One block per row; exactly one float4 per thread.
// ---------------------------------------------------------------------------
__global__ __launch_bounds__(256) void resln_kernel(
    const float* __restrict__ xin, const float* __restrict__ gamma,
    const float* __restrict__ beta, float* __restrict__ out)
{
    const int row = blockIdx.x;
    const int tid = threadIdx.x;
    const int wid = tid >> 6, lane = tid & 63;
    __shared__ float red[8];

    float4 x = *(const float4*)(xin + (size_t)row * HIDDEN + tid * 4);
    float s = x.x + x.y + x.z + x.w;
    #pragma unroll
    for (int off = 32; off > 0; off >>= 1) s += __shfl_xor(s, off, 64);
    if (lane == 0) red[wid] = s;
    __syncthreads();
    float mu = (red[0] + red[1] + red[2] + red[3]) * (1.f / HIDDEN);

    float dx = x.x - mu, dy = x.y - mu, dz = x.z - mu, dw = x.w - mu;
    float v = dx * dx + dy * dy + dz * dz + dw * dw;
    #pragma unroll
    for (int off = 32; off > 0; off >>= 1) v += __shfl_xor(v, off, 64);
    if (lane == 0) red[4 + wid] = v;
    __syncthreads();
    float var = (red[4] + red[5] + red[6] + red[7]) * (1.f / HIDDEN);
    float rstd = rsqrtf(var + EPS);

    float4 g = *(const float4*)(gamma + tid * 4);
    float4 bt = *(const float4*)(beta + tid * 4);
    float4 o;
    o.x = dx * rstd * g.x + bt.x;
    o.y = dy * rstd * g.y + bt.y;
    o.z = dz * rstd * g.z + bt.z;
    o.w = dw * rstd * g.w + bt.w;
    *(float4*)(out + (size_t)row * HIDDEN + tid * 4) = o;
}

// ---------------------------------------------------------------------------
extern "C" void kernel_launch(void* const* d_in, const int* in_sizes, int n_in,
                              void* d_out, int out_size, void* d_ws, size_t ws_size,
                              hipStream_t stream)
{
    const float* X     = (const float*)d_in[0];
    const float* Wq    = (const float*)d_in[1];
    const float* bq    = (const float*)d_in[2];
    const float* Wk    = (const float*)d_in[3];
    const float* bk    = (const float*)d_in[4];
    const float* Wv    = (const float*)d_in[5];
    const float* bv    = (const float*)d_in[6];
    const float* Wo    = (const float*)d_in[7];
    const float* bo    = (const float*)d_in[8];
    const float* gamma = (const float*)d_in[9];
    const float* beta  = (const float*)d_in[10];
    float* out = (float*)d_out;

    const int B = 2, S = 2048;
    const int M = B * S;                       // 4096
    const size_t mat = (size_t)M * HIDDEN;     // 4M elems

    // workspace map (peak 41 MB):
    //   [0,8)    Xb (dead after QKV gemm) -> VT overlays
    //   [8,10)   Wot
    //   [10,16)  Wt3 (3072x1024 bf16)
    //   [16,17)  b3
    //   [17,33)  QKb (dead after attn) -> Pj (fp32) overlays
    //   [33,41)  Vb (dead after vtrans) -> Ctx overlays
    char* ws = (char*)d_ws;
    short* Xb  = (short*)(ws);
    short* VT  = (short*)(ws);
    short* Wot = (short*)(ws + (8ull << 20));
    short* Wt3 = (short*)(ws + (10ull << 20));
    float* b3  = (float*)(ws + (16ull << 20));
    short* QKb = (short*)(ws + (17ull << 20));
    float* Pj  = (float*)(ws + (17ull << 20));
    short* Vb  = (short*)(ws + (33ull << 20));
    short* Ctx = (short*)(ws + (33ull << 20));

    dim3 blk(256);

    cast_bf16_kernel<<<dim3((int)(mat / 4 / 256)), blk, 0, stream>>>(X, Xb, (int)mat);
    wtrans_kernel<<<dim3(32, 32, 4), blk, 0, stream>>>(Wq, Wk, Wv, Wo, Wt3, Wot);
    concat_bias_kernel<<<12, blk, 0, stream>>>(bq, bk, bv, b3);

    // fused QKV projection: N=3072, V columns routed to Vb
    dim3 qkvgrid(3072 / 128, M / 128);         // (24, 32) = 768 blocks
    gemm_bt_mfma<<<qkvgrid, blk, 0, stream>>>(Xb, Wt3, b3,
                                              QKb, 2048, Vb, 2048, 1024,
                                              nullptr, M, 3072, HIDDEN, 1);

    vtranspose_kernel<<<dim3(16, 64), blk, 0, stream>>>(Vb, VT);

    dim3 agrid(HEADS, S / 64, B);              // (16, 32, 2) = 1024 blocks = 4/CU
    attn_mfma_kernel<<<agrid, blk, 0, stream>>>(QKb, VT, Ctx);

    // output projection + bias + residual (fp32 out)
    dim3 ogrid(HIDDEN / 128, M / 128);         // (8, 32)
    gemm_bt_mfma<<<ogrid, blk, 0, stream>>>(Ctx, Wot, bo,
                                            Pj, 1024, nullptr, 1 << 30, 0,
                                            X, M, HIDDEN, HIDDEN, 0);

    resln_kernel<<<M, blk, 0, stream>>>(Pj, gamma, beta, out);
}